// Round 1
// baseline (221.303 us; speedup 1.0000x reference)
//
#include <hip/hip_runtime.h>
#include <hip/hip_bf16.h>

// MultiHeadSelfAttention fwd: B=2, T=2048, C=768, H=12, D=64.
// Pipeline: [gemm_bt fp32->bf16 qkv] -> [flash attn bf16] -> [gemm_bt bf16->fp32 out]
// All matmuls use mfma_f32_16x16x32_bf16 (fp32 accum).

typedef __bf16 bf16;
typedef __attribute__((ext_vector_type(8))) __bf16 bf16x8;
typedef __attribute__((ext_vector_type(4))) float f32x4;

#define MFMA_BF16(a, b, c) __builtin_amdgcn_mfma_f32_16x16x32_bf16((a), (b), (c), 0, 0, 0)

static constexpr int BB = 2;      // batch
static constexpr int TT = 2048;   // seq len
static constexpr int CC = 768;    // hidden
static constexpr int HH = 12;     // heads
static constexpr int DD = 64;     // head dim

// ---- staging helpers: load 16 contiguous elements, emit 16 bf16 into LDS ----
__device__ inline void ld16(const float* __restrict__ src, bf16* dst) {
  const float4* s = (const float4*)src;
  float4 v0 = s[0], v1 = s[1], v2 = s[2], v3 = s[3];
  bf16x8 r0, r1;
  r0[0] = (bf16)v0.x; r0[1] = (bf16)v0.y; r0[2] = (bf16)v0.z; r0[3] = (bf16)v0.w;
  r0[4] = (bf16)v1.x; r0[5] = (bf16)v1.y; r0[6] = (bf16)v1.z; r0[7] = (bf16)v1.w;
  r1[0] = (bf16)v2.x; r1[1] = (bf16)v2.y; r1[2] = (bf16)v2.z; r1[3] = (bf16)v2.w;
  r1[4] = (bf16)v3.x; r1[5] = (bf16)v3.y; r1[6] = (bf16)v3.z; r1[7] = (bf16)v3.w;
  *(bf16x8*)dst = r0;
  *(bf16x8*)(dst + 8) = r1;
}
__device__ inline void ld16(const bf16* __restrict__ src, bf16* dst) {
  const bf16x8* s = (const bf16x8*)src;
  bf16x8 a = s[0], b = s[1];
  *(bf16x8*)dst = a;
  *(bf16x8*)(dst + 8) = b;
}

// ---- C = A * B^T + bias. A:[M,K] (fp32 or bf16), B:[N,K] fp32, C:[M,N] (OT) ----
// 128x128 tile, BK=32, 256 threads = 4 waves in 2x2, each wave 64x64 (4x4 frags).
template <typename AT, typename OT>
__global__ __launch_bounds__(256) void gemm_bt(const AT* __restrict__ A,
                                               const float* __restrict__ Bw,
                                               const float* __restrict__ bias,
                                               OT* __restrict__ Cmat,
                                               int M, int N, int K) {
  __shared__ bf16 As[128 * 32];
  __shared__ bf16 Bs[128 * 32];
  const int tid = threadIdx.x;
  const int m0 = blockIdx.y * 128, n0 = blockIdx.x * 128;
  const int lane = tid & 63, w = tid >> 6;
  const int wm = (w >> 1) * 64, wn = (w & 1) * 64;
  const int lr = lane & 15, lk = (lane >> 4) * 8;
  const int srow = tid >> 1, scol = (tid & 1) * 16;   // 256 thr * 16 elem = 4096
  f32x4 acc[4][4] = {};
  for (int k0 = 0; k0 < K; k0 += 32) {
    __syncthreads();
    ld16(A  + (size_t)(m0 + srow) * K + k0 + scol, As + srow * 32 + scol);
    ld16(Bw + (size_t)(n0 + srow) * K + k0 + scol, Bs + srow * 32 + scol);
    __syncthreads();
    bf16x8 a[4], b[4];
#pragma unroll
    for (int i = 0; i < 4; i++) a[i] = *(const bf16x8*)&As[(wm + i * 16 + lr) * 32 + lk];
#pragma unroll
    for (int j = 0; j < 4; j++) b[j] = *(const bf16x8*)&Bs[(wn + j * 16 + lr) * 32 + lk];
#pragma unroll
    for (int i = 0; i < 4; i++)
#pragma unroll
      for (int j = 0; j < 4; j++)
        acc[i][j] = MFMA_BF16(a[i], b[j], acc[i][j]);
  }
  // C/D layout (m89-verified): col = lane&15, row = (lane>>4)*4 + reg
#pragma unroll
  for (int i = 0; i < 4; i++) {
    const int rbase = m0 + wm + i * 16 + (lane >> 4) * 4;
#pragma unroll
    for (int j = 0; j < 4; j++) {
      const int cidx = n0 + wn + j * 16 + lr;
      const float bv = bias[cidx];
#pragma unroll
      for (int r = 0; r < 4; r++) {
        float v = acc[i][j][r] + bv;
        Cmat[(size_t)(rbase + r) * N + cidx] = (OT)v;
      }
    }
  }
}

// ---- flash attention over one (b, h, 64-row q block); 4 waves x 16 q rows ----
__global__ __launch_bounds__(256) void attn_fwd(const bf16* __restrict__ qkv,
                                                const int* __restrict__ mask,
                                                bf16* __restrict__ ctx) {
  __shared__ bf16 Qs[64 * 64];
  __shared__ bf16 Ks[64 * 64];
  __shared__ bf16 Vt[64 * 64];        // transposed: Vt[d][key]
  __shared__ bf16 Ps[4][16 * 64];     // per-wave P tile
  const int b = blockIdx.z, h = blockIdx.y, q0 = blockIdx.x * 64;
  const int tid = threadIdx.x, lane = tid & 63, w = tid >> 6;
  const int lr = lane & 15, lk = (lane >> 4) * 8;
  const int srow = tid >> 2, scol = (tid & 3) * 16;   // 256 thr * 16 = 4096
  const size_t rs = 3 * CC;                            // qkv row stride
  const float scale = 0.125f;                          // 1/sqrt(64)

  ld16(qkv + (size_t)(b * TT + q0 + srow) * rs + h * DD + scol, Qs + srow * 64 + scol);

  f32x4 oacc[4] = {};
  float mrow[4] = {-INFINITY, -INFINITY, -INFINITY, -INFINITY};
  float lsum[4] = {0.f, 0.f, 0.f, 0.f};

  for (int kt = 0; kt < TT; kt += 64) {
    __syncthreads();   // prev iter's PV done before restaging K/Vt
    ld16(qkv + (size_t)(b * TT + kt + srow) * rs + CC + h * DD + scol, Ks + srow * 64 + scol);
    {
      const bf16x8* vs = (const bf16x8*)(qkv + (size_t)(b * TT + kt + srow) * rs + 2 * CC + h * DD + scol);
      bf16x8 v0 = vs[0], v1 = vs[1];
#pragma unroll
      for (int i = 0; i < 8; i++) {
        Vt[(scol + i) * 64 + srow]     = v0[i];
        Vt[(scol + 8 + i) * 64 + srow] = v1[i];
      }
    }
    __syncthreads();

    // S = Q * K^T (wave's 16 q rows x 64 keys)
    f32x4 sacc[4] = {};
#pragma unroll
    for (int kk = 0; kk < 64; kk += 32) {
      bf16x8 aQ = *(const bf16x8*)&Qs[(w * 16 + lr) * 64 + kk + lk];
#pragma unroll
      for (int j = 0; j < 4; j++) {
        bf16x8 bK = *(const bf16x8*)&Ks[(j * 16 + lr) * 64 + kk + lk];
        sacc[j] = MFMA_BF16(aQ, bK, sacc[j]);
      }
    }

    // masked online softmax; row r lives in lanes sharing lane>>4, 16-lane shfl reduce
    int mk[4];
#pragma unroll
    for (int j = 0; j < 4; j++) mk[j] = mask[b * TT + kt + j * 16 + lr];
    float p[4][4];
#pragma unroll
    for (int r = 0; r < 4; r++) {
      float mx = mrow[r];
#pragma unroll
      for (int j = 0; j < 4; j++) {
        float s = sacc[j][r] * scale;
        s = mk[j] ? s : -INFINITY;
        p[j][r] = s;
        mx = fmaxf(mx, s);
      }
#pragma unroll
      for (int d = 1; d < 16; d <<= 1) mx = fmaxf(mx, __shfl_xor(mx, d));
      const float mnew = mx;
      const float al = (mnew == -INFINITY) ? 1.f : __expf(mrow[r] - mnew);
      float rsum = 0.f;
#pragma unroll
      for (int j = 0; j < 4; j++) {
        float pv = (p[j][r] == -INFINITY) ? 0.f : __expf(p[j][r] - mnew);
        p[j][r] = pv;
        rsum += pv;
      }
#pragma unroll
      for (int d = 1; d < 16; d <<= 1) rsum += __shfl_xor(rsum, d);
      lsum[r] = lsum[r] * al + rsum;
      mrow[r] = mnew;
#pragma unroll
      for (int j = 0; j < 4; j++) oacc[j][r] *= al;
    }

    // P -> per-wave LDS (A-fragment layout round trip); wave-internal, no barrier
#pragma unroll
    for (int r = 0; r < 4; r++)
#pragma unroll
      for (int j = 0; j < 4; j++)
        Ps[w][((lane >> 4) * 4 + r) * 64 + j * 16 + lr] = (bf16)p[j][r];

    // O += P * V
#pragma unroll
    for (int kk = 0; kk < 64; kk += 32) {
      bf16x8 aP = *(const bf16x8*)&Ps[w][lr * 64 + kk + lk];
#pragma unroll
      for (int j = 0; j < 4; j++) {
        bf16x8 bV = *(const bf16x8*)&Vt[(j * 16 + lr) * 64 + kk + lk];
        oacc[j] = MFMA_BF16(aP, bV, oacc[j]);
      }
    }
  }

  float inv[4];
#pragma unroll
  for (int r = 0; r < 4; r++) inv[r] = lsum[r] > 0.f ? 1.f / lsum[r] : 0.f;
#pragma unroll
  for (int j = 0; j < 4; j++)
#pragma unroll
    for (int r = 0; r < 4; r++) {
      const int row = q0 + w * 16 + (lane >> 4) * 4 + r;
      ctx[(size_t)(b * TT + row) * CC + h * DD + j * 16 + lr] = (bf16)(oacc[j][r] * inv[r]);
    }
}

extern "C" void kernel_launch(void* const* d_in, const int* in_sizes, int n_in,
                              void* d_out, int out_size, void* d_ws, size_t ws_size,
                              hipStream_t stream) {
  const float* x     = (const float*)d_in[0];
  const int*   mask  = (const int*)d_in[1];
  const float* w_qkv = (const float*)d_in[2];
  const float* b_qkv = (const float*)d_in[3];
  const float* w_out = (const float*)d_in[4];
  const float* b_out = (const float*)d_in[5];
  float* out = (float*)d_out;

  const int M = BB * TT;                 // 4096
  bf16* qkv = (bf16*)d_ws;               // [4096, 2304] bf16 = 18.9 MB
  bf16* ctx = qkv + (size_t)M * 3 * CC;  // [4096, 768]  bf16 = 6.3 MB

  gemm_bt<float, bf16><<<dim3(3 * CC / 128, M / 128), 256, 0, stream>>>(
      x, w_qkv, b_qkv, qkv, M, 3 * CC, CC);
  attn_fwd<<<dim3(TT / 64, HH, BB), 256, 0, stream>>>(qkv, mask, ctx);
  gemm_bt<bf16, float><<<dim3(CC / 128, M / 128), 256, 0, stream>>>(
      ctx, w_out, b_out, out, M, CC, CC);
}

// Round 2
// 190.373 us; speedup vs baseline: 1.1625x; 1.1625x over previous
//
#include <hip/hip_runtime.h>
#include <hip/hip_bf16.h>

// MultiHeadSelfAttention fwd: B=2, T=2048, C=768, H=12, D=64.
// [gemm_bt fp32->bf16 qkv] -> [flash attn bf16, swizzled LDS] -> [gemm_bt bf16->fp32 out]

typedef __bf16 bf16;
typedef __attribute__((ext_vector_type(8))) __bf16 bf16x8;
typedef __attribute__((ext_vector_type(8))) unsigned short u16x8;
typedef __attribute__((ext_vector_type(4))) float f32x4;
typedef __attribute__((ext_vector_type(4))) int i32x4;

#define MFMA_BF16(a, b, c) __builtin_amdgcn_mfma_f32_16x16x32_bf16((a), (b), (c), 0, 0, 0)

static constexpr int BB = 2;
static constexpr int TT = 2048;
static constexpr int CC = 768;
static constexpr int HH = 12;
static constexpr int DD = 64;

// XOR swizzle for 64-col bf16 LDS tiles (128B rows): flips 16B chunks within the row.
// Element-index granularity; same involution on write and read sides.
__device__ inline int esw(int row) { return (((row & 7) ^ ((row >> 3) & 7)) << 3); }

// ---- staging helpers: load 16 contiguous elements, emit 16 bf16 into LDS ----
__device__ inline void ld16(const float* __restrict__ src, bf16* dst) {
  const float4* s = (const float4*)src;
  float4 v0 = s[0], v1 = s[1], v2 = s[2], v3 = s[3];
  bf16x8 r0, r1;
  r0[0] = (bf16)v0.x; r0[1] = (bf16)v0.y; r0[2] = (bf16)v0.z; r0[3] = (bf16)v0.w;
  r0[4] = (bf16)v1.x; r0[5] = (bf16)v1.y; r0[6] = (bf16)v1.z; r0[7] = (bf16)v1.w;
  r1[0] = (bf16)v2.x; r1[1] = (bf16)v2.y; r1[2] = (bf16)v2.z; r1[3] = (bf16)v2.w;
  r1[4] = (bf16)v3.x; r1[5] = (bf16)v3.y; r1[6] = (bf16)v3.z; r1[7] = (bf16)v3.w;
  *(bf16x8*)dst = r0;
  *(bf16x8*)(dst + 8) = r1;
}
__device__ inline void ld16(const bf16* __restrict__ src, bf16* dst) {
  const bf16x8* s = (const bf16x8*)src;
  bf16x8 a = s[0], b = s[1];
  *(bf16x8*)dst = a;
  *(bf16x8*)(dst + 8) = b;
}

// ---- C = A * B^T + bias (unchanged from round 1) ----
template <typename AT, typename OT>
__global__ __launch_bounds__(256) void gemm_bt(const AT* __restrict__ A,
                                               const float* __restrict__ Bw,
                                               const float* __restrict__ bias,
                                               OT* __restrict__ Cmat,
                                               int M, int N, int K) {
  __shared__ bf16 As[128 * 32];
  __shared__ bf16 Bs[128 * 32];
  const int tid = threadIdx.x;
  const int m0 = blockIdx.y * 128, n0 = blockIdx.x * 128;
  const int lane = tid & 63, w = tid >> 6;
  const int wm = (w >> 1) * 64, wn = (w & 1) * 64;
  const int lr = lane & 15, lk = (lane >> 4) * 8;
  const int srow = tid >> 1, scol = (tid & 1) * 16;
  f32x4 acc[4][4] = {};
  for (int k0 = 0; k0 < K; k0 += 32) {
    __syncthreads();
    ld16(A  + (size_t)(m0 + srow) * K + k0 + scol, As + srow * 32 + scol);
    ld16(Bw + (size_t)(n0 + srow) * K + k0 + scol, Bs + srow * 32 + scol);
    __syncthreads();
    bf16x8 a[4], b[4];
#pragma unroll
    for (int i = 0; i < 4; i++) a[i] = *(const bf16x8*)&As[(wm + i * 16 + lr) * 32 + lk];
#pragma unroll
    for (int j = 0; j < 4; j++) b[j] = *(const bf16x8*)&Bs[(wn + j * 16 + lr) * 32 + lk];
#pragma unroll
    for (int i = 0; i < 4; i++)
#pragma unroll
      for (int j = 0; j < 4; j++)
        acc[i][j] = MFMA_BF16(a[i], b[j], acc[i][j]);
  }
#pragma unroll
  for (int i = 0; i < 4; i++) {
    const int rbase = m0 + wm + i * 16 + (lane >> 4) * 4;
#pragma unroll
    for (int j = 0; j < 4; j++) {
      const int cidx = n0 + wn + j * 16 + lr;
      const float bv = bias[cidx];
#pragma unroll
      for (int r = 0; r < 4; r++) {
        float v = acc[i][j][r] + bv;
        Cmat[(size_t)(rbase + r) * N + cidx] = (OT)v;
      }
    }
  }
}

// ---- flash attention: 64 q-rows/block, 4 waves x 16 rows, KV tile = 64 ----
// Q in registers; Ks/Vt/Ps swizzled; V transposed via pair-shuffle dword writes;
// next tile's K/V global loads issued before compute (T14 split).
__global__ __launch_bounds__(256) void attn_fwd(const bf16* __restrict__ qkv,
                                                const int* __restrict__ mask,
                                                bf16* __restrict__ ctx) {
  __shared__ bf16 Ks[64 * 64];
  __shared__ bf16 Vt[64 * 64];        // Vt[d][key], swizzled
  __shared__ bf16 Ps[4][16 * 64];     // per-wave P tile, swizzled
  const int b = blockIdx.z, h = blockIdx.y, q0 = blockIdx.x * 64;
  const int tid = threadIdx.x, lane = tid & 63, w = tid >> 6;
  const int lr = lane & 15, lk = (lane >> 4) * 8;
  const int srow = tid >> 2, scol = (tid & 3) * 16;
  const size_t rs = 3 * CC;
  const float SC = 0.125f * 1.44269504f;   // scale * log2(e)
  const float NEG = -1.0e30f;

  // Q fragments in registers (row = q0 + w*16 + lr)
  const bf16* qbase = qkv + (size_t)(b * TT + q0 + w * 16 + lr) * rs + h * DD;
  const bf16x8 aQ0 = *(const bf16x8*)(qbase + lk);
  const bf16x8 aQ1 = *(const bf16x8*)(qbase + 32 + lk);

  // per-thread staging source (row srow of the K/V tile, cols scol..scol+15)
  const bf16* ksrc = qkv + (size_t)(b * TT + srow) * rs + CC + h * DD + scol;
  const bf16* vsrc = qkv + (size_t)(b * TT + srow) * rs + 2 * CC + h * DD + scol;

  bf16x8 k0, k1, v0, v1;
  auto load_tiles = [&](int kt) {
    const bf16* kp = ksrc + (size_t)kt * rs;
    const bf16* vp = vsrc + (size_t)kt * rs;
    k0 = *(const bf16x8*)kp;  k1 = *(const bf16x8*)(kp + 8);
    v0 = *(const bf16x8*)vp;  v1 = *(const bf16x8*)(vp + 8);
  };
  auto write_tiles = [&]() {
    // K tile: two swizzled 16B chunks
    const int e0 = srow * 64 + scol, ek = esw(srow);
    *(bf16x8*)&Ks[e0 ^ ek] = k0;
    *(bf16x8*)&Ks[(e0 + 8) ^ ek] = k1;
    // V transpose: exchange with key-partner (lane^4), write key-pair dwords
    const int par = srow & 1;
    i32x4 x = par ? *(i32x4*)&v0 : *(i32x4*)&v1;   // even sends hi-d half, odd sends lo-d half
    i32x4 rr;
#pragma unroll
    for (int m = 0; m < 4; m++) rr[m] = __shfl_xor(x[m], 4);
    const u16x8 mine = par ? *(u16x8*)&v1 : *(u16x8*)&v0;
    const u16x8 rv = *(u16x8*)&rr;
    const int kp2 = srow & ~1;
#pragma unroll
    for (int m = 0; m < 8; m++) {
      const int d = scol + par * 8 + m;
      const unsigned int lo = par ? (unsigned int)rv[m] : (unsigned int)mine[m];
      const unsigned int hi = par ? (unsigned int)mine[m] : (unsigned int)rv[m];
      *(unsigned int*)&Vt[(d * 64 + kp2) ^ esw(d)] = lo | (hi << 16);
    }
  };

  load_tiles(0);
  write_tiles();
  __syncthreads();

  f32x4 oacc[4] = {};
  float mrow[4] = {NEG, NEG, NEG, NEG};
  float lsum[4] = {0.f, 0.f, 0.f, 0.f};

  for (int kt = 0; kt < TT; kt += 64) {
    const bool havenext = (kt + 64 < TT);
    if (havenext) load_tiles(kt + 64);     // issue early; consumed after barrier
    int mk[4];
#pragma unroll
    for (int j = 0; j < 4; j++) mk[j] = mask[b * TT + kt + j * 16 + lr];

    // S = Q K^T
    f32x4 sacc[4] = {};
#pragma unroll
    for (int j = 0; j < 4; j++) {
      const int row = j * 16 + lr, er = esw(row);
      bf16x8 bK0 = *(const bf16x8*)&Ks[(row * 64 + lk) ^ er];
      sacc[j] = MFMA_BF16(aQ0, bK0, sacc[j]);
      bf16x8 bK1 = *(const bf16x8*)&Ks[(row * 64 + 32 + lk) ^ er];
      sacc[j] = MFMA_BF16(aQ1, bK1, sacc[j]);
    }

    // online softmax (exp2 domain, finite sentinel)
    float p[4][4];
#pragma unroll
    for (int r = 0; r < 4; r++) {
      float mx = mrow[r];
#pragma unroll
      for (int j = 0; j < 4; j++) {
        float s = sacc[j][r] * SC;
        s = mk[j] ? s : NEG;
        p[j][r] = s;
        mx = fmaxf(mx, s);
      }
#pragma unroll
      for (int d = 1; d < 16; d <<= 1) mx = fmaxf(mx, __shfl_xor(mx, d));
      const float al = exp2f(mrow[r] - mx);
      float rsum = 0.f;
#pragma unroll
      for (int j = 0; j < 4; j++) {
        float pv = exp2f(p[j][r] - mx);
        p[j][r] = pv;
        rsum += pv;
      }
#pragma unroll
      for (int d = 1; d < 16; d <<= 1) rsum += __shfl_xor(rsum, d);
      lsum[r] = lsum[r] * al + rsum;
      mrow[r] = mx;
#pragma unroll
      for (int j = 0; j < 4; j++) oacc[j][r] *= al;
    }

    // P -> per-wave swizzled LDS (A-fragment layout round trip)
#pragma unroll
    for (int r = 0; r < 4; r++) {
      const int prow = (lane >> 4) * 4 + r;
      const int ep = esw(prow);
#pragma unroll
      for (int j = 0; j < 4; j++)
        Ps[w][(prow * 64 + j * 16 + lr) ^ ep] = (bf16)p[j][r];
    }

    // O += P V
#pragma unroll
    for (int kki = 0; kki < 2; kki++) {
      const int kk = kki * 32;
      bf16x8 aP = *(const bf16x8*)&Ps[w][(lr * 64 + kk + lk) ^ esw(lr)];
#pragma unroll
      for (int j = 0; j < 4; j++) {
        const int drow = j * 16 + lr;
        bf16x8 bV = *(const bf16x8*)&Vt[(drow * 64 + kk + lk) ^ esw(drow)];
        oacc[j] = MFMA_BF16(aP, bV, oacc[j]);
      }
    }

    __syncthreads();           // all waves done reading Ks/Vt
    if (havenext) write_tiles();
    __syncthreads();           // next tile staged
  }

  float inv[4];
#pragma unroll
  for (int r = 0; r < 4; r++) inv[r] = lsum[r] > 0.f ? 1.f / lsum[r] : 0.f;
#pragma unroll
  for (int j = 0; j < 4; j++)
#pragma unroll
    for (int r = 0; r < 4; r++) {
      const int row = q0 + w * 16 + (lane >> 4) * 4 + r;
      ctx[(size_t)(b * TT + row) * CC + h * DD + j * 16 + lr] = (bf16)(oacc[j][r] * inv[r]);
    }
}

extern "C" void kernel_launch(void* const* d_in, const int* in_sizes, int n_in,
                              void* d_out, int out_size, void* d_ws, size_t ws_size,
                              hipStream_t stream) {
  const float* x     = (const float*)d_in[0];
  const int*   mask  = (const int*)d_in[1];
  const float* w_qkv = (const float*)d_in[2];
  const float* b_qkv = (const float*)d_in[3];
  const float* w_out = (const float*)d_in[4];
  const float* b_out = (const float*)d_in[5];
  float* out = (float*)d_out;

  const int M = BB * TT;
  bf16* qkv = (bf16*)d_ws;
  bf16* ctx = qkv + (size_t)M * 3 * CC;

  gemm_bt<float, bf16><<<dim3(3 * CC / 128, M / 128), 256, 0, stream>>>(
      x, w_qkv, b_qkv, qkv, M, 3 * CC, CC);
  attn_fwd<<<dim3(TT / 64, HH, BB), 256, 0, stream>>>(qkv, mask, ctx);
  gemm_bt<bf16, float><<<dim3(CC / 128, M / 128), 256, 0, stream>>>(
      ctx, w_out, b_out, out, M, CC, CC);
}

// Round 3
// 183.753 us; speedup vs baseline: 1.2043x; 1.0360x over previous
//
#include <hip/hip_runtime.h>
#include <hip/hip_bf16.h>

// MultiHeadSelfAttention fwd: B=2, T=2048, C=768, H=12, D=64.
// [cvt f32->bf16] -> [gemm_bt bf16 (global_load_lds), Q pre-scaled] ->
// [flash attn bf16: dbuf LDS, mask-in-acc, defer-max] -> [gemm_bt bf16->f32]

typedef __bf16 bf16;
typedef __attribute__((ext_vector_type(8))) __bf16 bf16x8;
typedef __attribute__((ext_vector_type(8))) unsigned short u16x8;
typedef __attribute__((ext_vector_type(4))) float f32x4;
typedef __attribute__((ext_vector_type(4))) int i32x4;

#define MFMA_BF16(a, b, c) __builtin_amdgcn_mfma_f32_16x16x32_bf16((a), (b), (c), 0, 0, 0)

static constexpr int BB = 2;
static constexpr int TT = 2048;
static constexpr int CC = 768;
static constexpr int HH = 12;
static constexpr int DD = 64;

// XOR swizzle for 64-col bf16 LDS tiles (128B rows), 8-elem chunk granularity.
__device__ inline int esw(int row) { return (((row & 7) ^ ((row >> 3) & 7)) << 3); }

// async global->LDS, 16B per lane; lds dest must be wave-uniform base (HW adds lane*16)
__device__ inline void gload16(const bf16* g, bf16* l) {
  __builtin_amdgcn_global_load_lds((const __attribute__((address_space(1))) void*)g,
                                   (__attribute__((address_space(3))) void*)l, 16, 0, 0);
}

// ---- one-shot fp32 -> bf16 conversion of x, w_qkv, w_out ----
__global__ __launch_bounds__(256) void cvt_all(const float* __restrict__ x,
                                               const float* __restrict__ wq,
                                               const float* __restrict__ wo,
                                               bf16* __restrict__ xb,
                                               bf16* __restrict__ wqb,
                                               bf16* __restrict__ wob) {
  const int CX = BB * TT * CC / 8, CQ = 3 * CC * CC / 8;
  int idx = blockIdx.x * 256 + threadIdx.x;
  const float* s;
  bf16* d;
  int off;
  if (idx < CX) { s = x; d = xb; off = idx; }
  else if (idx < CX + CQ) { s = wq; d = wqb; off = idx - CX; }
  else { s = wo; d = wob; off = idx - CX - CQ; }
  const float4* p = (const float4*)(s + (size_t)off * 8);
  float4 a = p[0], b = p[1];
  bf16x8 r;
  r[0] = (bf16)a.x; r[1] = (bf16)a.y; r[2] = (bf16)a.z; r[3] = (bf16)a.w;
  r[4] = (bf16)b.x; r[5] = (bf16)b.y; r[6] = (bf16)b.z; r[7] = (bf16)b.w;
  *(bf16x8*)(d + (size_t)off * 8) = r;
}

// ---- C = A * B^T + bias; cols < qcols additionally scaled by qs ----
// 128x128 tile, BK=32, 4 waves 2x2, global_load_lds staging (m97 pattern).
template <typename OT>
__global__ __launch_bounds__(256) void gemm_bt_bf16(const bf16* __restrict__ A,
                                                    const bf16* __restrict__ Bw,
                                                    const float* __restrict__ bias,
                                                    OT* __restrict__ Cmat,
                                                    int M, int N, int K,
                                                    float qs, int qcols) {
  __shared__ bf16 As[128 * 32];
  __shared__ bf16 Bs[128 * 32];
  const int tid = threadIdx.x;
  const int m0 = blockIdx.y * 128, n0 = blockIdx.x * 128;
  const int lane = tid & 63, w = tid >> 6;
  const int wm = (w >> 1) * 64, wn = (w & 1) * 64;
  const int lr = lane & 15, lk = (lane >> 4) * 8;
  const int ar = lane >> 2, ac = (lane & 3) * 8;   // staging: 4 lanes/row, 8 elems each
  f32x4 acc[4][4] = {};
  for (int k0 = 0; k0 < K; k0 += 32) {
    __syncthreads();
#pragma unroll
    for (int c = 0; c < 2; c++) {
      const int ch = w * 2 + c;
      const int row = ch * 16 + ar;
      gload16(A  + (size_t)(m0 + row) * K + k0 + ac, &As[ch * 512]);
      gload16(Bw + (size_t)(n0 + row) * K + k0 + ac, &Bs[ch * 512]);
    }
    __syncthreads();
    bf16x8 a[4], b[4];
#pragma unroll
    for (int i = 0; i < 4; i++) a[i] = *(const bf16x8*)&As[(wm + i * 16 + lr) * 32 + lk];
#pragma unroll
    for (int j = 0; j < 4; j++) b[j] = *(const bf16x8*)&Bs[(wn + j * 16 + lr) * 32 + lk];
#pragma unroll
    for (int i = 0; i < 4; i++)
#pragma unroll
      for (int j = 0; j < 4; j++)
        acc[i][j] = MFMA_BF16(a[i], b[j], acc[i][j]);
  }
#pragma unroll
  for (int i = 0; i < 4; i++) {
    const int rbase = m0 + wm + i * 16 + (lane >> 4) * 4;
#pragma unroll
    for (int j = 0; j < 4; j++) {
      const int cidx = n0 + wn + j * 16 + lr;
      const float bv = bias[cidx];
      const float sc = (cidx < qcols) ? qs : 1.0f;
#pragma unroll
      for (int r = 0; r < 4; r++) {
        float v = (acc[i][j][r] + bv) * sc;
        Cmat[(size_t)(rbase + r) * N + cidx] = (OT)v;
      }
    }
  }
}

// ---- flash attention: 64 q-rows/block, 4 waves x 16 rows, KV tile 64, dbuf ----
__global__ __launch_bounds__(256) void attn_fwd(const bf16* __restrict__ qkv,
                                                const int* __restrict__ mask,
                                                bf16* __restrict__ ctx) {
  __shared__ bf16 Ks[2][64 * 64];
  __shared__ bf16 Vt[2][64 * 64];     // Vt[d][key], swizzled
  __shared__ bf16 Ps[4][16 * 72];     // per-wave P tile, stride-72 rows
  const int b = blockIdx.z, h = blockIdx.y, q0 = blockIdx.x * 64;
  const int tid = threadIdx.x, lane = tid & 63, w = tid >> 6;
  const int lr = lane & 15, lk = (lane >> 4) * 8;
  const int srow = tid >> 2, scol = (tid & 3) * 16;
  const size_t rs = 3 * CC;
  const float NEG = -1.0e30f;

  // Q fragments in registers; Q already pre-scaled by 0.125*log2(e) in qkv GEMM
  const bf16* qbase = qkv + (size_t)(b * TT + q0 + w * 16 + lr) * rs + h * DD;
  const bf16x8 aQ0 = *(const bf16x8*)(qbase + lk);
  const bf16x8 aQ1 = *(const bf16x8*)(qbase + 32 + lk);

  const bf16* ksrc = qkv + (size_t)(b * TT + srow) * rs + CC + h * DD + scol;
  const bf16* vsrc = qkv + (size_t)(b * TT + srow) * rs + 2 * CC + h * DD + scol;
  const int* msrc = mask + b * TT + lr;

  bf16x8 k0, k1, v0, v1;
  int mn[4];
  auto load_tiles = [&](int kt) {
    const bf16* kp = ksrc + (size_t)kt * rs;
    const bf16* vp = vsrc + (size_t)kt * rs;
    k0 = ((const bf16x8*)kp)[0]; k1 = ((const bf16x8*)kp)[1];
    v0 = ((const bf16x8*)vp)[0]; v1 = ((const bf16x8*)vp)[1];
#pragma unroll
    for (int j = 0; j < 4; j++) mn[j] = msrc[kt + j * 16];
  };
  auto write_tiles = [&](int buf) {
    const int e0 = srow * 64 + scol, ek = esw(srow);
    *(bf16x8*)&Ks[buf][e0 ^ ek] = k0;
    *(bf16x8*)&Ks[buf][(e0 + 8) ^ ek] = k1;
    const int par = srow & 1;
    i32x4 xch = par ? *(i32x4*)&v0 : *(i32x4*)&v1;
    i32x4 rrv;
#pragma unroll
    for (int m2 = 0; m2 < 4; m2++) rrv[m2] = __shfl_xor(xch[m2], 4);
    const u16x8 mine = par ? *(u16x8*)&v1 : *(u16x8*)&v0;
    const u16x8 rv = *(u16x8*)&rrv;
    const int kp2 = srow & ~1;
#pragma unroll
    for (int m2 = 0; m2 < 8; m2++) {
      const int d = scol + par * 8 + m2;
      const unsigned lo = par ? (unsigned)rv[m2] : (unsigned)mine[m2];
      const unsigned hi = par ? (unsigned)mine[m2] : (unsigned)rv[m2];
      *(unsigned*)&Vt[buf][(d * 64 + kp2) ^ esw(d)] = lo | (hi << 16);
    }
  };

  load_tiles(0);
  write_tiles(0);
  int mc[4];
#pragma unroll
  for (int j = 0; j < 4; j++) mc[j] = mn[j];
  __syncthreads();

  f32x4 oacc[4] = {};
  float mrow[4] = {NEG, NEG, NEG, NEG};
  float lsum[4] = {0.f, 0.f, 0.f, 0.f};

  int cur = 0;
  for (int kt = 0; kt < TT; kt += 64, cur ^= 1) {
    const bool havenext = (kt + 64 < TT);
    if (havenext) load_tiles(kt + 64);

    // S = Q K^T, mask folded into accumulator init (scores already in log2 units)
    f32x4 sacc[4];
#pragma unroll
    for (int j = 0; j < 4; j++) {
      const float ma = mc[j] ? 0.f : NEG;
      sacc[j] = (f32x4){ma, ma, ma, ma};
    }
#pragma unroll
    for (int j = 0; j < 4; j++) {
      const int row = j * 16 + lr, er = esw(row);
      bf16x8 bK0 = *(const bf16x8*)&Ks[cur][(row * 64 + lk) ^ er];
      sacc[j] = MFMA_BF16(aQ0, bK0, sacc[j]);
      bf16x8 bK1 = *(const bf16x8*)&Ks[cur][(row * 64 + 32 + lk) ^ er];
      sacc[j] = MFMA_BF16(aQ1, bK1, sacc[j]);
    }

    // online softmax with defer-max (T13): skip reduce+rescale when max stable
    float p[4][4], smax[4];
    float need = 0.f;
#pragma unroll
    for (int r = 0; r < 4; r++) {
      smax[r] = fmaxf(fmaxf(sacc[0][r], sacc[1][r]), fmaxf(sacc[2][r], sacc[3][r]));
      need = fmaxf(need, smax[r] - mrow[r]);
    }
    if (__all(need <= 8.f)) {
#pragma unroll
      for (int r = 0; r < 4; r++) {
        float rsum = 0.f;
#pragma unroll
        for (int j = 0; j < 4; j++) {
          float pv = exp2f(sacc[j][r] - mrow[r]);
          p[j][r] = pv;
          rsum += pv;
        }
#pragma unroll
        for (int d = 1; d < 16; d <<= 1) rsum += __shfl_xor(rsum, d);
        lsum[r] += rsum;
      }
    } else {
#pragma unroll
      for (int r = 0; r < 4; r++) {
        float mx = fmaxf(mrow[r], smax[r]);
#pragma unroll
        for (int d = 1; d < 16; d <<= 1) mx = fmaxf(mx, __shfl_xor(mx, d));
        const float al = exp2f(mrow[r] - mx);
        float rsum = 0.f;
#pragma unroll
        for (int j = 0; j < 4; j++) {
          float pv = exp2f(sacc[j][r] - mx);
          p[j][r] = pv;
          rsum += pv;
        }
#pragma unroll
        for (int d = 1; d < 16; d <<= 1) rsum += __shfl_xor(rsum, d);
        lsum[r] = lsum[r] * al + rsum;
        mrow[r] = mx;
#pragma unroll
        for (int j = 0; j < 4; j++) oacc[j][r] *= al;
      }
    }

    // P -> per-wave LDS (stride-72 rows: write ~2-way, read aligned 16B)
#pragma unroll
    for (int r = 0; r < 4; r++) {
      const int prow = (lane >> 4) * 4 + r;
#pragma unroll
      for (int j = 0; j < 4; j++)
        Ps[w][prow * 72 + j * 16 + lr] = (bf16)p[j][r];
    }

    // O += P V
#pragma unroll
    for (int kki = 0; kki < 2; kki++) {
      const int kk = kki * 32;
      bf16x8 aP = *(const bf16x8*)&Ps[w][lr * 72 + kk + lk];
#pragma unroll
      for (int j = 0; j < 4; j++) {
        const int drow = j * 16 + lr;
        bf16x8 bV = *(const bf16x8*)&Vt[cur][(drow * 64 + kk + lk) ^ esw(drow)];
        oacc[j] = MFMA_BF16(aP, bV, oacc[j]);
      }
    }

    if (havenext) {
      write_tiles(cur ^ 1);   // other buffer: safe while others still read cur
#pragma unroll
      for (int j = 0; j < 4; j++) mc[j] = mn[j];
    }
    __syncthreads();
  }

  float inv[4];
#pragma unroll
  for (int r = 0; r < 4; r++) inv[r] = lsum[r] > 0.f ? 1.f / lsum[r] : 0.f;
#pragma unroll
  for (int j = 0; j < 4; j++)
#pragma unroll
    for (int r = 0; r < 4; r++) {
      const int row = q0 + w * 16 + (lane >> 4) * 4 + r;
      ctx[(size_t)(b * TT + row) * CC + h * DD + j * 16 + lr] = (bf16)(oacc[j][r] * inv[r]);
    }
}

extern "C" void kernel_launch(void* const* d_in, const int* in_sizes, int n_in,
                              void* d_out, int out_size, void* d_ws, size_t ws_size,
                              hipStream_t stream) {
  const float* x     = (const float*)d_in[0];
  const int*   mask  = (const int*)d_in[1];
  const float* w_qkv = (const float*)d_in[2];
  const float* b_qkv = (const float*)d_in[3];
  const float* w_out = (const float*)d_in[4];
  const float* b_out = (const float*)d_in[5];
  float* out = (float*)d_out;

  const int M = BB * TT;  // 4096
  // ws layout (bf16 elems): qkv | {xb,ctx lifetime-overlapped} | wqb | wob  = 29.9 MB
  bf16* qkv = (bf16*)d_ws;                     // [4096,2304]
  bf16* xb  = qkv + (size_t)M * 3 * CC;        // [4096,768]
  bf16* ctx = xb;                              // reuses xb region (xb dead after gemm1)
  bf16* wqb = xb + (size_t)M * CC;             // [2304,768]
  bf16* wob = wqb + (size_t)3 * CC * CC;       // [768,768]

  const int nchunks = (BB * TT * CC + 3 * CC * CC + CC * CC) / 8;  // 688128
  cvt_all<<<nchunks / 256, 256, 0, stream>>>(x, w_qkv, w_out, xb, wqb, wob);
  gemm_bt_bf16<bf16><<<dim3(3 * CC / 128, M / 128), 256, 0, stream>>>(
      xb, wqb, b_qkv, qkv, M, 3 * CC, CC, 0.125f * 1.44269504f, CC);
  attn_fwd<<<dim3(TT / 64, HH, BB), 256, 0, stream>>>(qkv, mask, ctx);
  gemm_bt_bf16<float><<<dim3(CC / 128, M / 128), 256, 0, stream>>>(
      ctx, wob, b_out, out, M, CC, CC, 1.0f, 0);
}

// Round 4
// 159.658 us; speedup vs baseline: 1.3861x; 1.1509x over previous
//
#include <hip/hip_runtime.h>
#include <hip/hip_bf16.h>

// MultiHeadSelfAttention fwd: B=2, T=2048, C=768, H=12, D=64.
// [cvt f32->bf16] -> [gemm_bt bf16 (global_load_lds), Q pre-scaled by 0.125*log2e] ->
// [flash attn, 32x32 swapped-QK^T, in-register softmax (T12), dbuf, 1 barrier/tile] ->
// [gemm_bt bf16->f32]

typedef __bf16 bf16;
typedef __attribute__((ext_vector_type(4))) __bf16 bf16x4;
typedef __attribute__((ext_vector_type(8))) __bf16 bf16x8;
typedef __attribute__((ext_vector_type(4))) float f32x4;
typedef __attribute__((ext_vector_type(16))) float f32x16;
typedef __attribute__((ext_vector_type(4))) unsigned u32x4;

#define MFMA16(a, b, c) __builtin_amdgcn_mfma_f32_16x16x32_bf16((a), (b), (c), 0, 0, 0)
#define MFMA32(a, b, c) __builtin_amdgcn_mfma_f32_32x32x16_bf16((a), (b), (c), 0, 0, 0)

static constexpr int BB = 2;
static constexpr int TT = 2048;
static constexpr int CC = 768;
static constexpr int HH = 12;
static constexpr int DD = 64;

union U8 { u32x4 u; bf16x8 b; };

// async global->LDS, 16B per lane; LDS dest wave-uniform base (HW adds lane*16)
__device__ inline void gload16(const bf16* g, bf16* l) {
  __builtin_amdgcn_global_load_lds((const __attribute__((address_space(1))) void*)g,
                                   (__attribute__((address_space(3))) void*)l, 16, 0, 0);
}

// ---- one-shot fp32 -> bf16 conversion of x, w_qkv, w_out ----
__global__ __launch_bounds__(256) void cvt_all(const float* __restrict__ x,
                                               const float* __restrict__ wq,
                                               const float* __restrict__ wo,
                                               bf16* __restrict__ xb,
                                               bf16* __restrict__ wqb,
                                               bf16* __restrict__ wob) {
  const int CX = BB * TT * CC / 8, CQ = 3 * CC * CC / 8;
  int idx = blockIdx.x * 256 + threadIdx.x;
  const float* s;
  bf16* d;
  int off;
  if (idx < CX) { s = x; d = xb; off = idx; }
  else if (idx < CX + CQ) { s = wq; d = wqb; off = idx - CX; }
  else { s = wo; d = wob; off = idx - CX - CQ; }
  const float4* p = (const float4*)(s + (size_t)off * 8);
  float4 a = p[0], b = p[1];
  bf16x8 r;
  r[0] = (bf16)a.x; r[1] = (bf16)a.y; r[2] = (bf16)a.z; r[3] = (bf16)a.w;
  r[4] = (bf16)b.x; r[5] = (bf16)b.y; r[6] = (bf16)b.z; r[7] = (bf16)b.w;
  *(bf16x8*)(d + (size_t)off * 8) = r;
}

// ---- C = A * B^T + bias; cols < qcols additionally scaled by qs ----
template <typename OT>
__global__ __launch_bounds__(256) void gemm_bt_bf16(const bf16* __restrict__ A,
                                                    const bf16* __restrict__ Bw,
                                                    const float* __restrict__ bias,
                                                    OT* __restrict__ Cmat,
                                                    int M, int N, int K,
                                                    float qs, int qcols) {
  __shared__ bf16 As[128 * 32];
  __shared__ bf16 Bs[128 * 32];
  const int tid = threadIdx.x;
  const int m0 = blockIdx.y * 128, n0 = blockIdx.x * 128;
  const int lane = tid & 63, w = tid >> 6;
  const int wm = (w >> 1) * 64, wn = (w & 1) * 64;
  const int lr = lane & 15, lk = (lane >> 4) * 8;
  const int ar = lane >> 2, ac = (lane & 3) * 8;
  f32x4 acc[4][4] = {};
  for (int k0 = 0; k0 < K; k0 += 32) {
    __syncthreads();
#pragma unroll
    for (int c = 0; c < 2; c++) {
      const int ch = w * 2 + c;
      const int row = ch * 16 + ar;
      gload16(A  + (size_t)(m0 + row) * K + k0 + ac, &As[ch * 512]);
      gload16(Bw + (size_t)(n0 + row) * K + k0 + ac, &Bs[ch * 512]);
    }
    __syncthreads();
    bf16x8 a[4], b[4];
#pragma unroll
    for (int i = 0; i < 4; i++) a[i] = *(const bf16x8*)&As[(wm + i * 16 + lr) * 32 + lk];
#pragma unroll
    for (int j = 0; j < 4; j++) b[j] = *(const bf16x8*)&Bs[(wn + j * 16 + lr) * 32 + lk];
#pragma unroll
    for (int i = 0; i < 4; i++)
#pragma unroll
      for (int j = 0; j < 4; j++)
        acc[i][j] = MFMA16(a[i], b[j], acc[i][j]);
  }
#pragma unroll
  for (int i = 0; i < 4; i++) {
    const int rbase = m0 + wm + i * 16 + (lane >> 4) * 4;
#pragma unroll
    for (int j = 0; j < 4; j++) {
      const int cidx = n0 + wn + j * 16 + lr;
      const float bv = bias[cidx];
      const float sc = (cidx < qcols) ? qs : 1.0f;
#pragma unroll
      for (int r = 0; r < 4; r++) {
        float v = (acc[i][j][r] + bv) * sc;
        Cmat[(size_t)(rbase + r) * N + cidx] = (OT)v;
      }
    }
  }
}

// ---- flash attention, swapped-QK^T 32x32 structure ----
// 768 blocks x 128 threads (2 warps x 32 q-rows). KV tile 32, dbuf, 1 barrier/tile.
// S^T = mfma(K, Q^T): lane owns q=lane&31 column; softmax in-register;
// P -> PV B-frag via cvt_pk + permlane32_swap (T12). O^T = mfma(V^T, P).
__global__ __launch_bounds__(128) void attn_fwd(const bf16* __restrict__ qkv,
                                                const int* __restrict__ mask,
                                                bf16* __restrict__ ctx) {
  __shared__ bf16 Ks[2][32 * 64];   // [key][d], chunk-swizzled
  __shared__ bf16 Vt[2][64 * 32];   // [d][key], chunk-swizzled
  const int tid = threadIdx.x, lane = tid & 63, w = tid >> 6;
  const int ln31 = lane & 31, hi = lane >> 5;
  // XCD-aware bijective swizzle (768 = 8*96)
  const int bid = blockIdx.x;
  const int wg = (bid & 7) * 96 + (bid >> 3);
  const int qb = wg & 31, bh = wg >> 5;
  const int h = bh % HH, b = bh / HH;
  const int q = qb * 64 + w * 32 + ln31;
  const size_t rs = 3 * CC;
  const float NEG = -1.0e30f;

  // Q fragments (B-operand): lane holds Q[q][ds*16 + hi*8 + 0..7], pre-scaled in GEMM
  bf16x8 qreg[4];
  {
    const bf16* qp = qkv + (size_t)(b * TT + q) * rs + h * DD + hi * 8;
#pragma unroll
    for (int ds = 0; ds < 4; ds++) qreg[ds] = *(const bf16x8*)(qp + ds * 16);
  }

  const bf16* kbase = qkv + (size_t)(b * TT) * rs + CC + h * DD;
  const bf16* vbase = qkv + (size_t)(b * TT) * rs + 2 * CC + h * DD;

  // K staging: global_load_lds, source pre-swizzled so linear LDS == swizzled layout
  auto stage_k = [&](int buf, int kt) {
#pragma unroll
    for (int s = 0; s < 2; s++) {
      const int bk = w * 16 + s * 8;
      const int key = bk + (lane >> 3);
      const int cs = (lane & 7) ^ (key & 7) ^ (key >> 3);
      gload16(kbase + (size_t)(kt + key) * rs + cs * 8, &Ks[buf][bk * 64]);
    }
  };

  // V staging: reg load (issue early), pair-shuffle transpose + swizzled dword writes (late)
  const int vkey0 = tid >> 3;        // 0..15
  const int d0 = (tid & 7) * 8;
  const int par = vkey0 & 1;
  bf16x8 vreg0, vreg1;
  int mv;
  auto load_v = [&](int kt) {
    vreg0 = *(const bf16x8*)(vbase + (size_t)(kt + vkey0) * rs + d0);
    vreg1 = *(const bf16x8*)(vbase + (size_t)(kt + vkey0 + 16) * rs + d0);
    mv = mask[b * TT + kt + ln31];
  };
  auto vt_put = [&](int buf, int d, int kp, unsigned val) {
    const int cp = (kp >> 2) ^ (d & 3) ^ ((d >> 2) & 3);
    *(unsigned*)&Vt[buf][d * 32 + cp * 8 + (kp & 3) * 2] = val;
  };
  auto write_v = [&](int buf) {
#pragma unroll
    for (int half = 0; half < 2; half++) {
      const int key = vkey0 + half * 16;
      const int kp = key >> 1;
      U8 uu; uu.b = half ? vreg1 : vreg0;
      const u32x4 wv = uu.u;
      unsigned x0 = par ? wv[0] : wv[2];
      unsigned x1 = par ? wv[1] : wv[3];
      unsigned r0 = __shfl_xor(x0, 8);
      unsigned r1 = __shfl_xor(x1, 8);
      // a* = even-key words for my d-range, b* = odd-key words
      unsigned a0 = par ? r0 : wv[0];
      unsigned a1 = par ? r1 : wv[1];
      unsigned b0 = par ? wv[2] : r0;
      unsigned b1 = par ? wv[3] : r1;
      const int dbase = d0 + par * 4;
      vt_put(buf, dbase + 0, kp, (a0 & 0xffffu) | (b0 << 16));
      vt_put(buf, dbase + 1, kp, (a0 >> 16) | (b0 & 0xffff0000u));
      vt_put(buf, dbase + 2, kp, (a1 & 0xffffu) | (b1 << 16));
      vt_put(buf, dbase + 3, kp, (a1 >> 16) | (b1 & 0xffff0000u));
    }
  };

  stage_k(0, 0);
  load_v(0);
  write_v(0);
  __syncthreads();   // drains K DMA too
  int mvc = mv;

  f32x16 oacc0 = {}, oacc1 = {};
  float m = NEG, l = 0.f;
  const int swr = (ln31 & 7) ^ (ln31 >> 3);
  const int vsw = (ln31 & 3) ^ ((ln31 >> 2) & 3);

  int cur = 0;
  for (int kt = 0; kt < TT; kt += 32, cur ^= 1) {
    const bool more = kt + 32 < TT;
    if (more) { stage_k(cur ^ 1, kt + 32); load_v(kt + 32); }

    // S^T[key][q] accumulate: A = K-frag (row=key), B = Q-frag (col=q)
    f32x16 sacc = {};
#pragma unroll
    for (int ds = 0; ds < 4; ds++) {
      bf16x8 kf = *(const bf16x8*)&Ks[cur][ln31 * 64 + ((ds * 2 + hi) ^ swr) * 8];
      sacc = MFMA32(kf, qreg[ds], sacc);
    }

    // mask (wave-uniform fast path for all-ones tiles)
    const unsigned mw = (unsigned)__ballot(mvc != 0);
    if (mw != 0xffffffffu) {
      const unsigned mwh = mw >> (4 * hi);
#pragma unroll
      for (int r = 0; r < 16; r++) {
        const int key = (r & 3) + 8 * (r >> 2);
        if (!((mwh >> key) & 1)) sacc[r] = NEG;
      }
    }

    // in-register softmax (scores already in log2 domain); defer-max THR=8
    float mx = sacc[0];
#pragma unroll
    for (int r = 1; r < 16; r++) mx = fmaxf(mx, sacc[r]);
    mx = fmaxf(mx, __shfl_xor(mx, 32));
    if (!__all(mx - m <= 8.f)) {
      const float al = exp2f(m - mx);
      l *= al;
#pragma unroll
      for (int r = 0; r < 16; r++) { oacc0[r] *= al; oacc1[r] *= al; }
      m = mx;
    }
    float p[16], rsum = 0.f;
#pragma unroll
    for (int r = 0; r < 16; r++) { p[r] = exp2f(sacc[r] - m); rsum += p[r]; }
    rsum += __shfl_xor(rsum, 32);
    l += rsum;

    // P -> bf16 PV B-frags in-register: 8 cvt_pk + 4 permlane32_swap (T12)
    unsigned pk[8];
#pragma unroll
    for (int i = 0; i < 8; i++)
      asm("v_cvt_pk_bf16_f32 %0, %1, %2" : "=v"(pk[i]) : "v"(p[2 * i]), "v"(p[2 * i + 1]));
    asm volatile("v_permlane32_swap_b32 %0, %1" : "+v"(pk[0]), "+v"(pk[2]));
    asm volatile("v_permlane32_swap_b32 %0, %1" : "+v"(pk[1]), "+v"(pk[3]));
    asm volatile("v_permlane32_swap_b32 %0, %1" : "+v"(pk[4]), "+v"(pk[6]));
    asm volatile("v_permlane32_swap_b32 %0, %1" : "+v"(pk[5]), "+v"(pk[7]));

    // O^T += V^T * P  (A = V^T frag row=d, B = P frag col=q)
#pragma unroll
    for (int ks = 0; ks < 2; ks++) {
      U8 uu;
      uu.u = (u32x4){pk[ks * 4 + 0], pk[ks * 4 + 1], pk[ks * 4 + 2], pk[ks * 4 + 3]};
      const bf16x8 pb = uu.b;
      const int cph = ((ks * 2 + hi) ^ vsw) * 8;
      bf16x8 vf0 = *(const bf16x8*)&Vt[cur][ln31 * 32 + cph];
      oacc0 = MFMA32(vf0, pb, oacc0);
      bf16x8 vf1 = *(const bf16x8*)&Vt[cur][(32 + ln31) * 32 + cph];
      oacc1 = MFMA32(vf1, pb, oacc1);
    }

    if (more) write_v(cur ^ 1);
    __syncthreads();
    mvc = mv;
  }

  // epilogue: O^T[d][q] -> ctx[q][d], normalized; d = dt*32 + 8g + 4hi + (0..3)
  const float invl = l > 0.f ? 1.0f / l : 0.f;
  bf16* obase = ctx + (size_t)(b * TT + q) * CC + h * DD;
#pragma unroll
  for (int g = 0; g < 4; g++) {
    bf16x4 o0, o1;
#pragma unroll
    for (int j = 0; j < 4; j++) {
      o0[j] = (bf16)(oacc0[4 * g + j] * invl);
      o1[j] = (bf16)(oacc1[4 * g + j] * invl);
    }
    *(bf16x4*)(obase + 8 * g + 4 * hi) = o0;
    *(bf16x4*)(obase + 32 + 8 * g + 4 * hi) = o1;
  }
}

extern "C" void kernel_launch(void* const* d_in, const int* in_sizes, int n_in,
                              void* d_out, int out_size, void* d_ws, size_t ws_size,
                              hipStream_t stream) {
  const float* x     = (const float*)d_in[0];
  const int*   mask  = (const int*)d_in[1];
  const float* w_qkv = (const float*)d_in[2];
  const float* b_qkv = (const float*)d_in[3];
  const float* w_out = (const float*)d_in[4];
  const float* b_out = (const float*)d_in[5];
  float* out = (float*)d_out;

  const int M = BB * TT;  // 4096
  bf16* qkv = (bf16*)d_ws;                     // [4096,2304]
  bf16* xb  = qkv + (size_t)M * 3 * CC;        // [4096,768]
  bf16* ctx = xb;                              // reuse (xb dead after gemm1)
  bf16* wqb = xb + (size_t)M * CC;             // [2304,768]
  bf16* wob = wqb + (size_t)3 * CC * CC;       // [768,768]

  const int nchunks = (BB * TT * CC + 3 * CC * CC + CC * CC) / 8;
  cvt_all<<<nchunks / 256, 256, 0, stream>>>(x, w_qkv, w_out, xb, wqb, wob);
  gemm_bt_bf16<bf16><<<dim3(3 * CC / 128, M / 128), 256, 0, stream>>>(
      xb, wqb, b_qkv, qkv, M, 3 * CC, CC, 0.125f * 1.44269504f, CC);
  attn_fwd<<<dim3(768), 128, 0, stream>>>(qkv, mask, ctx);
  gemm_bt_bf16<float><<<dim3(CC / 128, M / 128), 256, 0, stream>>>(
      ctx, wob, b_out, out, M, CC, CC, 1.0f, 0);
}